// Round 6
// baseline (374.368 us; speedup 1.0000x reference)
//
#include <hip/hip_runtime.h>
#include <stdint.h>

// Problem constants
#define B_ 4
#define S_ 2048
#define E_ 1024
#define H_ 16
#define HD_ 64

typedef __attribute__((ext_vector_type(8))) short bf16x8;   // 8 bf16 = 4 VGPRs (MFMA A/B frag)
typedef __attribute__((ext_vector_type(4))) float f32x4;    // MFMA C/D frag

__device__ __forceinline__ ushort f2b(float f) {
    union { float f; uint32_t u; } c; c.f = f;
    return (ushort)((c.u + 0x8000u) >> 16);   // round-to-nearest (ties up)
}

// pack two f32 -> {bf16(a) lo, bf16(b) hi} (2 add + 1 v_perm).
// NOTE: v_cvt_pk_bf16_f32 was tried here (round 1) and FAILED correctness
// (absmax 9.8e-3 ~= adjacent-P-swap signature) -- its operand packing does not
// match this layout. Keep the perm-based pack.
__device__ __forceinline__ uint32_t pkbf(float a, float b) {
    union { float f; uint32_t u; } ca, cb; ca.f = a; cb.f = b;
#if __has_builtin(__builtin_amdgcn_perm)
    return __builtin_amdgcn_perm(cb.u + 0x8000u, ca.u + 0x8000u, 0x07060302u);
#else
    return (uint32_t)f2b(a) | ((uint32_t)f2b(b) << 16);
#endif
}

#if __has_builtin(__builtin_amdgcn_exp2f)
#define EXP2(x) __builtin_amdgcn_exp2f(x)
#else
#define EXP2(x) exp2f(x)
#endif

// async global->LDS, 16B per lane; LDS dest = wave-uniform base + lane*16,
// global src = PER-LANE address (gather) -> source-side permutations are free.
__device__ __forceinline__ void gl2lds16(const ushort* g, const ushort* l) {
    __builtin_amdgcn_global_load_lds(
        (const __attribute__((address_space(1))) unsigned int*)g,
        (__attribute__((address_space(3))) unsigned int*)l,
        16, 0, 0);
}

// ---------------------------------------------------------------- fused converts
// x (2097152 float4) + Wqkv (786432) + Wo (262144) in one launch
__global__ __launch_bounds__(256) void cvt_all(
    const float* __restrict__ x, const float* __restrict__ wq, const float* __restrict__ wo,
    ushort* __restrict__ xb, ushort* __restrict__ wqb, ushort* __restrict__ wob) {
    int i = blockIdx.x * 256 + threadIdx.x;
    const float* src; ushort* dst; int off;
    if (i < 2097152)      { src = x;  dst = xb;  off = i; }
    else if (i < 2883584) { src = wq; dst = wqb; off = i - 2097152; }
    else                  { src = wo; dst = wob; off = i - 2883584; }
    float4 f = ((const float4*)src)[off];
    ushort4 o;
    o.x = f2b(f.x); o.y = f2b(f.y); o.z = f2b(f.z); o.w = f2b(f.w);
    ((ushort4*)dst)[off] = o;
}

// mask [B,S,S] int32 (0/1) -> bit-packed, kt-major:
// mb[((b*32 + kt)*2048 + q)*2 + w] bit c = mask[b][q][kt*64 + w*32 + c]
__global__ __launch_bounds__(256) void pack_mask(const int* __restrict__ mask,
                                                 uint32_t* __restrict__ mb) {
    int i = blockIdx.x * 256 + threadIdx.x;   // 16777216 threads
    unsigned long long bal = __ballot(mask[i] == 1);
    int lane = threadIdx.x & 63;
    if (lane < 2) {
        int b = i >> 22, q = (i >> 11) & 2047, c = i & 2047;
        int kt = c >> 6;
        mb[((uint64_t)(b * 32 + kt) * 2048 + q) * 2 + lane] =
            (lane == 0) ? (uint32_t)bal : (uint32_t)(bal >> 32);
    }
}

// ---------------------------------------------------------------- GEMM core (dist-2 ring)
// Measured round 5: neutral vs 2-barrier (consistent with m97-structure ceiling);
// kept (not worse, and FETCH-friendly with the XCD swizzle).
template <int KD>
__device__ __forceinline__ void gemm_bt_core(
    const ushort* __restrict__ A, const ushort* __restrict__ Bm,
    int m0, int n0, ushort* L, f32x4 (&acc)[4][4])
{
    constexpr int NST = KD / 32;            // K-steps (32 for KD=1024)
    const int tid  = threadIdx.x;
    const int lane = tid & 63;
    const int wave = tid >> 6;
    const int wm = wave >> 1, wn = wave & 1;
    const int fr = lane & 15;
    const int fk = (lane >> 4) * 8;
    const int lrow = lane >> 2;
    const int lk   = (lane & 3) * 8;

    const f32x4 fz = {0.f, 0.f, 0.f, 0.f};
#pragma unroll
    for (int i = 0; i < 4; ++i)
#pragma unroll
        for (int j = 0; j < 4; ++j) acc[i][j] = fz;

    // ring slots (8192 ushorts each: As at +0, Bs at +4096)
    ushort* s0 = L;
    ushort* s1 = L + 8192;
    ushort* s2 = L + 16384;

    const uint64_t arow = (uint64_t)(m0 + lrow) * KD + lk;
    const uint64_t brow = (uint64_t)(n0 + lrow) * KD + lk;

#define GEMM_STAGE(k0, slot)                                                     \
    {                                                                            \
        _Pragma("unroll")                                                        \
        for (int t = 0; t < 2; ++t) {                                            \
            const int r0 = t * 64 + wave * 16;                                   \
            gl2lds16(&A [arow + (uint64_t)r0 * KD + (k0)], &(slot)[r0 * 32]);    \
            gl2lds16(&Bm[brow + (uint64_t)r0 * KD + (k0)], &(slot)[4096 + r0 * 32]); \
        }                                                                        \
    }

    GEMM_STAGE(0, s0);
    GEMM_STAGE(32, s1);
    asm volatile("s_waitcnt vmcnt(4)" ::: "memory");
    __builtin_amdgcn_s_barrier();
    __builtin_amdgcn_sched_barrier(0);

    ushort* cur = s0; ushort* nxt = s1; ushort* tgt = s2;

    for (int kt = 0; kt < NST; ++kt) {
        if (kt < NST - 2) GEMM_STAGE((kt + 2) * 32, tgt);

        bf16x8 af[4], bfr[4];
#pragma unroll
        for (int i = 0; i < 4; ++i)
            af[i] = *(const bf16x8*)&cur[(wm * 64 + i * 16 + fr) * 32 + fk];
#pragma unroll
        for (int j = 0; j < 4; ++j)
            bfr[j] = *(const bf16x8*)&cur[4096 + (wn * 64 + j * 16 + fr) * 32 + fk];
        __builtin_amdgcn_s_setprio(1);
#pragma unroll
        for (int i = 0; i < 4; ++i)
#pragma unroll
            for (int j = 0; j < 4; ++j)
                acc[i][j] = __builtin_amdgcn_mfma_f32_16x16x32_bf16(af[i], bfr[j], acc[i][j], 0, 0, 0);
        __builtin_amdgcn_s_setprio(0);

        if (kt < NST - 2) {
            asm volatile("s_waitcnt vmcnt(4)" ::: "memory");
        } else {
            asm volatile("s_waitcnt vmcnt(0)" ::: "memory");
        }
        __builtin_amdgcn_s_barrier();
        __builtin_amdgcn_sched_barrier(0);

        ushort* o = cur; cur = nxt; nxt = tgt; tgt = o;
    }
#undef GEMM_STAGE
}

// ---------------------------------------------------------------- QKV GEMM
// Q pre-scaled by 0.125*log2(e): scores exit QK^T in log2 domain (exp2 softmax).
// 1D grid (1536 blocks) + bijective XCD swizzle.
__global__ __launch_bounds__(256) void qkv_gemm(
    const ushort* __restrict__ xb, const ushort* __restrict__ wb,
    const float* __restrict__ bqkv,
    ushort* __restrict__ qo, ushort* __restrict__ ko, ushort* __restrict__ vto)
{
    __shared__ __align__(16) ushort L[24576];   // 48 KB ring
    f32x4 acc[4][4];
    const int lin = blockIdx.x;                  // 1536 = 8 * 192
    const int swz = (lin & 7) * 192 + (lin >> 3);
    const int m0 = (swz & 63) * 128;
    const int n0 = (swz >> 6) * 128;
    gemm_bt_core<1024>(xb, wb, m0, n0, L, acc);

    const int lane = threadIdx.x & 63, wave = threadIdx.x >> 6;
    const int wm = wave >> 1, wn = wave & 1;
    const int col = lane & 15, rg = lane >> 4;
    const float QSC = 0.125f * 1.4426950408889634f;
#pragma unroll
    for (int j = 0; j < 4; ++j) {
        const int n = n0 + wn * 64 + j * 16 + col;
        const int h = n / 192, f = n % 192;
        const float bias = bqkv[n];
#pragma unroll
        for (int i2 = 0; i2 < 4; ++i2) {
            const int mbase = m0 + wm * 64 + i2 * 16 + rg * 4;
            if (f < 128) {
#pragma unroll
                for (int v = 0; v < 4; ++v) {
                    const int m = mbase + v;
                    const int b = m >> 11, s = m & 2047;
                    const float val = acc[i2][j][v] + bias;
                    if (f < 64) qo[((uint64_t)(b * 16 + h) * 2048 + s) * 64 + f]        = f2b(val * QSC);
                    else        ko[((uint64_t)(b * 16 + h) * 2048 + s) * 64 + (f - 64)] = f2b(val);
                }
            } else {
                const int b = mbase >> 11, s = mbase & 2047;
                ushort4 pk;
                pk.x = f2b(acc[i2][j][0] + bias);
                pk.y = f2b(acc[i2][j][1] + bias);
                pk.z = f2b(acc[i2][j][2] + bias);
                pk.w = f2b(acc[i2][j][3] + bias);
                *(ushort4*)&vto[((uint64_t)(b * 16 + h) * 64 + (f - 128)) * 2048 + s] = pk;
            }
        }
    }
}

// ---------------------------------------------------------------- flash attention v10
// v9 + LDS 48->40 KB for 4 blocks/CU (zero tail, occupancy 25->~40%):
//  * K keeps the 3-slot distance-2 ring (consumed at phase START).
//  * V moves to a 2-slot distance-1 double-buffer (consumed LATE in the phase,
//    at PV -- issue at kt-start, consume at kt+1's PV = ~1.5 phases of slack).
//  * vmcnt accounting: per phase issue V[kt+1] FIRST (pinned by sched_barrier),
//    then K[kt+2] + mask[kt+2]; end-of-phase vmcnt(4) keeps only the newest 4
//    (K+mask) in flight => V[kt+1] and K[kt+1] guaranteed landed.
//  * WAR safe: the V slot written at kt was last read at kt-1's PV, whose
//    ds_reads completed before the kt-1 barrier.
__global__ __launch_bounds__(256, 4) void attn_kernel(
    const ushort* __restrict__ qa, const ushort* __restrict__ ka,
    const ushort* __restrict__ vta, const uint32_t* __restrict__ mbits,
    ushort* __restrict__ ctxo)
{
    __shared__ __align__(16) ushort LDSH[20480];   // 40 KB: K ring 24 KB + V dbuf 16 KB
    ushort* const Ka0 = LDSH;                      // K ring slots (sigma rows, swizzled units)
    ushort* const Ka1 = LDSH + 4096;
    ushort* const Ka2 = LDSH + 8192;
    ushort* const Va0 = LDSH + 12288;              // V^T dbuf slots [64][64]
    ushort* const Va1 = LDSH + 16384;
    ushort* const CTX = LDSH;                      // 16 KB epilogue stage aliases K ring

    // XCD swizzle: XCD = bid%8 (round-robin dispatch); give each XCD 8 bh x 16 qb
    const int bid = blockIdx.x;
    const int bh = (bid & 7) * 8 + (bid >> 7);
    const int qb = (bid >> 3) & 15;
    const int b = bh >> 4;
    const int tid = threadIdx.x, lane = tid & 63, wave = tid >> 6;
    const int col = lane & 15, rg = lane >> 4;

    const uint64_t bhoff = (uint64_t)bh * (S_ * 64);
    const ushort* qp = qa + bhoff + (uint64_t)qb * 128 * 64;
    const ushort* kp = ka + bhoff;
    const ushort* vp = vta + bhoff;                       // [64][2048]
    // mask words for this thread's two q-rows (i=0 -> mk0, i=1 -> mk1)
    const uint32_t* mk0 = mbits + ((uint64_t)(b * 32) * 2048 + qb * 128 + wave * 32 + col) * 2;
    const uint32_t* mk1 = mk0 + 32;                       // +16 rows

    // staging geometry: 8 LDS rows / instruction; per-lane source gather
    const int lr = lane >> 3;                 // row within 8-row group (= r&7)
    const int usw = (lane & 7) ^ lr;          // XOR-swizzled 16B unit
    const int r0s = wave * 16 + lr;           // t=0 LDS row
    const int r1s = r0s + 8;                  // t=1 LDS row
    // sigma(r): bits (k2,jj,rg,v) -> (k2,rg,jj,v)
    const int sg0 = (r0s & 32) | ((r0s & 12) << 1) | ((r0s & 16) >> 2) | (r0s & 3);
    const int sg1 = (r1s & 32) | ((r1s & 12) << 1) | ((r1s & 16) >> 2) | (r1s & 3);
    const int kb0 = sg0 * 64 + usw * 8;       // K source offsets (element units)
    const int kb1 = sg1 * 64 + usw * 8;
    const int vb0 = r0s * 2048 + usw * 8;     // V source offsets (rows natural)
    const int vb1 = r1s * 2048 + usw * 8;
    const int ldst0 = wave * 1024;            // LDS dst (elements)
    const int ldst1 = ldst0 + 512;

    // Q fragments straight from global (16B loads; no LDS round-trip)
    bf16x8 aq[2][2];
#pragma unroll
    for (int i = 0; i < 2; ++i)
#pragma unroll
        for (int k2 = 0; k2 < 2; ++k2)
            aq[i][k2] = *(const bf16x8*)&qp[(wave * 32 + i * 16 + col) * 64 + k2 * 32 + rg * 8];

    // prologue: K[0]->Ka0, V[0]->Va0, K[1]->Ka1; masks kt=0/1 -> regs.
    gl2lds16(&kp[kb0], &Ka0[ldst0]);
    gl2lds16(&kp[kb1], &Ka0[ldst1]);
    gl2lds16(&vp[vb0], &Va0[ldst0]);
    gl2lds16(&vp[vb1], &Va0[ldst1]);
    gl2lds16(&kp[4096 + kb0], &Ka1[ldst0]);
    gl2lds16(&kp[4096 + kb1], &Ka1[ldst1]);
    uint2 m_cur0 = *(const uint2*)mk0;
    uint2 m_cur1 = *(const uint2*)mk1;
    uint2 m_nxt0 = *(const uint2*)(mk0 + 4096);
    uint2 m_nxt1 = *(const uint2*)(mk1 + 4096);
    uint2 m_new0 = m_nxt0, m_new1 = m_nxt1;
    // one-time full drain (keeps the count math simple; loop never drains early)
    asm volatile("s_waitcnt vmcnt(0)" ::: "memory");
    __builtin_amdgcn_s_barrier();
    __builtin_amdgcn_sched_barrier(0);

    const f32x4 fz = {0.f, 0.f, 0.f, 0.f};
    f32x4 acc[4][2];                      // ctx^T: row=d, col=q (q = wave*32 + i*16 + col)
#pragma unroll
    for (int dt = 0; dt < 4; ++dt)
#pragma unroll
        for (int i = 0; i < 2; ++i) acc[dt][i] = fz;
    f32x4 acc5[2] = {fz, fz};             // softmax denominator via ones-MFMA

    bf16x8 vone;
#pragma unroll
    for (int e = 0; e < 8; ++e) vone[e] = (short)0x3F80;   // bf16 1.0

    // precomputed single-bit masks: bit position rg*8 + p*4 + v
    uint32_t bsel[2][4];
#pragma unroll
    for (int p = 0; p < 2; ++p)
#pragma unroll
        for (int v = 0; v < 4; ++v) bsel[p][v] = 1u << (rg * 8 + p * 4 + v);

    const int u0 = (rg ^ (col & 7)) << 3; // fragment read offset (k-units 0..31); other half ^32

    // K ring: cK read at kt; nK = landing for kt+1; tK = issue target kt+2.
    // V dbuf: cV read at kt (PV); nV = issue target kt+1.
    const ushort* cK = Ka0; const ushort* nK = Ka1; ushort* tK = Ka2;
    const ushort* cV = Va0; ushort* nV = Va1;

    for (int kt = 0; kt < 32; ++kt) {
        // (1) V[kt+1] -> nV, distance 1 (consumed at kt+1's PV). MUST be the
        // oldest vmem of this phase: sched_barrier pins it before K/mask.
        if (kt < 31) {
            gl2lds16(&vp[vb0 + (kt + 1) * 64], &nV[ldst0]);
            gl2lds16(&vp[vb1 + (kt + 1) * 64], &nV[ldst1]);
        }
        __builtin_amdgcn_sched_barrier(0);
        // (2) K[kt+2] -> tK, distance 2; mask[kt+2] -> regs
        if (kt < 30) {
            const int k2 = (kt + 2) * 4096;
            gl2lds16(&kp[k2 + kb0], &tK[ldst0]);
            gl2lds16(&kp[k2 + kb1], &tK[ldst1]);
            m_new0 = *(const uint2*)(mk0 + (uint64_t)(kt + 2) * 4096);
            m_new1 = *(const uint2*)(mk1 + (uint64_t)(kt + 2) * 4096);
        }

        // scores S^T (log2 domain) vs sigma-permuted keys
        f32x4 sc[2][4];
        __builtin_amdgcn_s_setprio(1);
#pragma unroll
        for (int j = 0; j < 4; ++j) {
            bf16x8 bk0 = *(const bf16x8*)&cK[(j * 16 + col) * 64 + u0];
            bf16x8 bk1 = *(const bf16x8*)&cK[(j * 16 + col) * 64 + (u0 ^ 32)];
#pragma unroll
            for (int i = 0; i < 2; ++i) {
                f32x4 z = __builtin_amdgcn_mfma_f32_16x16x32_bf16(bk0, aq[i][0], fz, 0, 0, 0);
                sc[i][j] = __builtin_amdgcn_mfma_f32_16x16x32_bf16(bk1, aq[i][1], z, 0, 0, 0);
            }
        }
        __builtin_amdgcn_s_setprio(0);

        // mask + exp2; pack P directly into PV B-fragments (registers only).
        // key held = (j&2)*16 + rg*8 + (j&1)*4 + v -> word j&2, bit rg*8+(j&1)*4+v.
        bf16x8 bp[2][2];
#pragma unroll
        for (int i = 0; i < 2; ++i) {
            const uint2 mw = i ? m_cur1 : m_cur0;
            union { uint32_t w[4]; bf16x8 v; } p0, p1;
#pragma unroll
            for (int j = 0; j < 4; ++j) {
                const uint32_t w = (j & 2) ? mw.y : mw.x;
                const int p = j & 1;
                float pe[4];
#pragma unroll
                for (int v = 0; v < 4; ++v) {
                    const float s = (w & bsel[p][v]) ? 0.f : sc[i][j][v];
                    pe[v] = EXP2(s);
                }
                const uint32_t lo = pkbf(pe[0], pe[1]);
                const uint32_t hi = pkbf(pe[2], pe[3]);
                if (j < 2) { p0.w[p * 2] = lo; p0.w[p * 2 + 1] = hi; }
                else       { p1.w[p * 2] = lo; p1.w[p * 2 + 1] = hi; }
            }
            bp[i][0] = p0.v;
            bp[i][1] = p1.v;
        }

        // PV: acc[d][q] += Vt[d][k] * P[q][k]; denominator via ones-row MFMA
        __builtin_amdgcn_s_setprio(1);
#pragma unroll
        for (int i = 0; i < 2; ++i) {
            acc5[i] = __builtin_amdgcn_mfma_f32_16x16x32_bf16(vone, bp[i][0], acc5[i], 0, 0, 0);
            acc5[i] = __builtin_amdgcn_mfma_f32_16x16x32_bf16(vone, bp[i][1], acc5[i], 0, 0, 0);
        }
#pragma unroll
        for (int dt = 0; dt < 4; ++dt) {
            bf16x8 av0 = *(const bf16x8*)&cV[(dt * 16 + col) * 64 + u0];
            bf16x8 av1 = *(const bf16x8*)&cV[(dt * 16 + col) * 64 + (u0 ^ 32)];
#pragma unroll
            for (int i = 0; i < 2; ++i) {
                acc[dt][i] = __builtin_amdgcn_mfma_f32_16x16x32_bf16(av0, bp[i][0], acc[dt][i], 0, 0, 0);
                acc[dt][i] = __builtin_amdgcn_mfma_f32_16x16x32_bf16(av1, bp[i][1], acc[dt][i], 0, 0, 0);
            }
        }
        __builtin_amdgcn_s_setprio(0);

        // counted-vmcnt barrier: keep only the newest 4 (K[kt+2] + mask[kt+2])
        // in flight => V[kt+1] (issued first this phase) and K[kt+1] (older)
        // are guaranteed landed for the next phase.
        if (kt < 30) {
            asm volatile("s_waitcnt vmcnt(4)" ::: "memory");
        } else {
            asm volatile("s_waitcnt vmcnt(0)" ::: "memory");
        }
        __builtin_amdgcn_s_barrier();
        __builtin_amdgcn_sched_barrier(0);

        // rotate K ring, swap V dbuf, shift mask regs
        const ushort* oK = cK;
        cK = nK; nK = tK; tK = (ushort*)oK;
        ushort* oV = (ushort*)cV; cV = nV; nV = oV;
        m_cur0 = m_nxt0; m_cur1 = m_nxt1; m_nxt0 = m_new0; m_nxt1 = m_new1;
    }

    // 1/l per q=col lane: every row of acc5 equals the denominator (ones-matrix rows)
    float linv[2];
#pragma unroll
    for (int i = 0; i < 2; ++i) linv[i] = 1.0f / acc5[i][0];

    // transpose ctx^T back through CTX (swizzled) for coalesced global store.
    // CTX aliases the K ring: all K reads completed before the final barrier.
#pragma unroll
    for (int dt = 0; dt < 4; ++dt)
#pragma unroll
        for (int i = 0; i < 2; ++i) {
            const int q = wave * 32 + i * 16 + col;
            const int d = dt * 16 + rg * 4;
            const int gg = (d >> 3) ^ (q & 7);
            ushort4 pk;
            pk.x = f2b(acc[dt][i][0] * linv[i]);
            pk.y = f2b(acc[dt][i][1] * linv[i]);
            pk.z = f2b(acc[dt][i][2] * linv[i]);
            pk.w = f2b(acc[dt][i][3] * linv[i]);
            *(ushort4*)&CTX[q * 64 + gg * 8 + (d & 7)] = pk;
        }
    __syncthreads();
    const int h = bh & 15;
    const uint64_t obase = (uint64_t)(b * S_ + qb * 128) * E_ + (uint64_t)h * 64;
#pragma unroll
    for (int t4 = 0; t4 < 4; ++t4) {
        const int id = tid + t4 * 256;
        const int r = id >> 3, c8 = id & 7;
        *(bf16x8*)&ctxo[obase + (uint64_t)r * E_ + c8 * 8] =
            *(const bf16x8*)&CTX[r * 64 + ((c8 ^ (r & 7)) << 3)];
    }
}

// ---------------------------------------------------------------- output GEMM
// 1D grid (512 blocks) + bijective XCD swizzle (512 = 8 * 64).
__global__ __launch_bounds__(256) void out_gemm(
    const ushort* __restrict__ ctxb, const ushort* __restrict__ wob,
    const float* __restrict__ bo, float* __restrict__ out)
{
    __shared__ __align__(16) ushort L[24576];   // 48 KB ring
    f32x4 acc[4][4];
    const int lin = blockIdx.x;
    const int swz = (lin & 7) * 64 + (lin >> 3);
    const int m0 = (swz & 63) * 128;
    const int n0 = (swz >> 6) * 128;
    gemm_bt_core<1024>(ctxb, wob, m0, n0, L, acc);

    const int lane = threadIdx.x & 63, wave = threadIdx.x >> 6;
    const int wm = wave >> 1, wn = wave & 1;
    const int col = lane & 15, rg = lane >> 4;
#pragma unroll
    for (int j = 0; j < 4; ++j) {
        const int n = n0 + wn * 64 + j * 16 + col;
        const float bias = bo[n];
#pragma unroll
        for (int i2 = 0; i2 < 4; ++i2) {
            const int mb2 = m0 + wm * 64 + i2 * 16 + rg * 4;
#pragma unroll
            for (int v = 0; v < 4; ++v)
                out[(uint64_t)(mb2 + v) * 1024 + n] = acc[i2][j][v] + bias;
        }
    }
}

// ---------------------------------------------------------------- launch
extern "C" void kernel_launch(void* const* d_in, const int* in_sizes, int n_in,
                              void* d_out, int out_size, void* d_ws, size_t ws_size,
                              hipStream_t stream)
{
    const float* x    = (const float*)d_in[0];
    const int*   mask = (const int*)d_in[1];
    const float* Wqkv = (const float*)d_in[2];
    const float* bqkv = (const float*)d_in[3];
    const float* Wo   = (const float*)d_in[4];
    const float* bo   = (const float*)d_in[5];
    float* out = (float*)d_out;

    char* p = (char*)d_ws;
    ushort* xb  = (ushort*)p; p += (size_t)8388608 * 2;   // x bf16 [8192][1024]
    ushort* wqb = (ushort*)p; p += (size_t)3145728 * 2;   // Wqkv bf16 [3072][1024]
    ushort* wob = (ushort*)p; p += (size_t)1048576 * 2;   // Wo bf16 [1024][1024]
    ushort* qo  = (ushort*)p; p += (size_t)8388608 * 2;   // Q bf16 (log2-domain prescale)
    ushort* ko  = (ushort*)p; p += (size_t)8388608 * 2;   // K bf16 [bh][s][64]
    ushort* vto = (ushort*)p; p += (size_t)8388608 * 2;   // V^T bf16 [bh][64][s]
    ushort* ctx = (ushort*)p; p += (size_t)8388608 * 2;   // ctx bf16 [8192][1024]
    uint32_t* mb = (uint32_t*)p;                          // packed mask bits (kt-major), 2 MB

    cvt_all<<<12288, 256, 0, stream>>>(x, Wqkv, Wo, xb, wqb, wob);
    pack_mask<<<65536, 256, 0, stream>>>(mask, mb);
    qkv_gemm<<<1536, 256, 0, stream>>>(xb, wqb, bqkv, qo, ko, vto);
    attn_kernel<<<1024, 256, 0, stream>>>(qo, ko, vto, mb, ctx);
    out_gemm<<<512, 256, 0, stream>>>(ctx, wob, bo, out);
}

// Round 7
// 353.319 us; speedup vs baseline: 1.0596x; 1.0596x over previous
//
#include <hip/hip_runtime.h>
#include <stdint.h>

// Problem constants
#define B_ 4
#define S_ 2048
#define E_ 1024
#define H_ 16
#define HD_ 64

typedef __attribute__((ext_vector_type(8))) short bf16x8;   // 8 bf16 = 4 VGPRs (MFMA A/B frag)
typedef __attribute__((ext_vector_type(4))) float f32x4;    // MFMA C/D frag

__device__ __forceinline__ ushort f2b(float f) {
    union { float f; uint32_t u; } c; c.f = f;
    return (ushort)((c.u + 0x8000u) >> 16);   // round-to-nearest (ties up)
}

// truncating pack: two f32 -> {bf16_trunc(a) lo, bf16_trunc(b) hi} in ONE v_perm.
// Used ONLY for P in attn: the same truncated P feeds numerator (PV) and
// denominator (ones-MFMA), so the <=2^-8 truncation bias cancels in the ratio.
// (v_cvt_pk_bf16_f32 was tried round 1 and FAILED correctness; do not revisit
// without an isolated probe.)
__device__ __forceinline__ uint32_t pkbf_t(float a, float b) {
    union { float f; uint32_t u; } ca, cb; ca.f = a; cb.f = b;
#if __has_builtin(__builtin_amdgcn_perm)
    return __builtin_amdgcn_perm(cb.u, ca.u, 0x07060302u);
#else
    return (ca.u >> 16) | (cb.u & 0xFFFF0000u);
#endif
}

// all-ones iff bit `pos` of wn is set (1 op: v_bfe_i32)
__device__ __forceinline__ uint32_t keepmask(uint32_t wn, int pos) {
#if __has_builtin(__builtin_amdgcn_sbfe)
    return (uint32_t)__builtin_amdgcn_sbfe((int)wn, pos, 1);
#else
    return (uint32_t)(((int32_t)(wn << (31 - pos))) >> 31);
#endif
}

#if __has_builtin(__builtin_amdgcn_exp2f)
#define EXP2(x) __builtin_amdgcn_exp2f(x)
#else
#define EXP2(x) exp2f(x)
#endif

// async global->LDS, 16B per lane; LDS dest = wave-uniform base + lane*16,
// global src = PER-LANE address (gather) -> source-side permutations are free.
__device__ __forceinline__ void gl2lds16(const ushort* g, const ushort* l) {
    __builtin_amdgcn_global_load_lds(
        (const __attribute__((address_space(1))) unsigned int*)g,
        (__attribute__((address_space(3))) unsigned int*)l,
        16, 0, 0);
}

// ---------------------------------------------------------------- fused converts
// x (2097152 float4) + Wqkv (786432) + Wo (262144) in one launch
__global__ __launch_bounds__(256) void cvt_all(
    const float* __restrict__ x, const float* __restrict__ wq, const float* __restrict__ wo,
    ushort* __restrict__ xb, ushort* __restrict__ wqb, ushort* __restrict__ wob) {
    int i = blockIdx.x * 256 + threadIdx.x;
    const float* src; ushort* dst; int off;
    if (i < 2097152)      { src = x;  dst = xb;  off = i; }
    else if (i < 2883584) { src = wq; dst = wqb; off = i - 2097152; }
    else                  { src = wo; dst = wob; off = i - 2883584; }
    float4 f = ((const float4*)src)[off];
    ushort4 o;
    o.x = f2b(f.x); o.y = f2b(f.y); o.z = f2b(f.z); o.w = f2b(f.w);
    ((ushort4*)dst)[off] = o;
}

// mask [B,S,S] int32 (0/1) -> bit-packed, kt-major:
// mb[((b*32 + kt)*2048 + q)*2 + w] bit c = mask[b][q][kt*64 + w*32 + c]
__global__ __launch_bounds__(256) void pack_mask(const int* __restrict__ mask,
                                                 uint32_t* __restrict__ mb) {
    int i = blockIdx.x * 256 + threadIdx.x;   // 16777216 threads
    unsigned long long bal = __ballot(mask[i] == 1);
    int lane = threadIdx.x & 63;
    if (lane < 2) {
        int b = i >> 22, q = (i >> 11) & 2047, c = i & 2047;
        int kt = c >> 6;
        mb[((uint64_t)(b * 32 + kt) * 2048 + q) * 2 + lane] =
            (lane == 0) ? (uint32_t)bal : (uint32_t)(bal >> 32);
    }
}

// ---------------------------------------------------------------- GEMM core (dist-2 ring)
// Measured round 5: neutral vs 2-barrier (consistent with m97-structure ceiling);
// kept (not worse, and FETCH-friendly with the XCD swizzle).
template <int KD>
__device__ __forceinline__ void gemm_bt_core(
    const ushort* __restrict__ A, const ushort* __restrict__ Bm,
    int m0, int n0, ushort* L, f32x4 (&acc)[4][4])
{
    constexpr int NST = KD / 32;            // K-steps (32 for KD=1024)
    const int tid  = threadIdx.x;
    const int lane = tid & 63;
    const int wave = tid >> 6;
    const int wm = wave >> 1, wn = wave & 1;
    const int fr = lane & 15;
    const int fk = (lane >> 4) * 8;
    const int lrow = lane >> 2;
    const int lk   = (lane & 3) * 8;

    const f32x4 fz = {0.f, 0.f, 0.f, 0.f};
#pragma unroll
    for (int i = 0; i < 4; ++i)
#pragma unroll
        for (int j = 0; j < 4; ++j) acc[i][j] = fz;

    // ring slots (8192 ushorts each: As at +0, Bs at +4096)
    ushort* s0 = L;
    ushort* s1 = L + 8192;
    ushort* s2 = L + 16384;

    const uint64_t arow = (uint64_t)(m0 + lrow) * KD + lk;
    const uint64_t brow = (uint64_t)(n0 + lrow) * KD + lk;

#define GEMM_STAGE(k0, slot)                                                     \
    {                                                                            \
        _Pragma("unroll")                                                        \
        for (int t = 0; t < 2; ++t) {                                            \
            const int r0 = t * 64 + wave * 16;                                   \
            gl2lds16(&A [arow + (uint64_t)r0 * KD + (k0)], &(slot)[r0 * 32]);    \
            gl2lds16(&Bm[brow + (uint64_t)r0 * KD + (k0)], &(slot)[4096 + r0 * 32]); \
        }                                                                        \
    }

    GEMM_STAGE(0, s0);
    GEMM_STAGE(32, s1);
    asm volatile("s_waitcnt vmcnt(4)" ::: "memory");
    __builtin_amdgcn_s_barrier();
    __builtin_amdgcn_sched_barrier(0);

    ushort* cur = s0; ushort* nxt = s1; ushort* tgt = s2;

    for (int kt = 0; kt < NST; ++kt) {
        if (kt < NST - 2) GEMM_STAGE((kt + 2) * 32, tgt);

        bf16x8 af[4], bfr[4];
#pragma unroll
        for (int i = 0; i < 4; ++i)
            af[i] = *(const bf16x8*)&cur[(wm * 64 + i * 16 + fr) * 32 + fk];
#pragma unroll
        for (int j = 0; j < 4; ++j)
            bfr[j] = *(const bf16x8*)&cur[4096 + (wn * 64 + j * 16 + fr) * 32 + fk];
        __builtin_amdgcn_s_setprio(1);
#pragma unroll
        for (int i = 0; i < 4; ++i)
#pragma unroll
            for (int j = 0; j < 4; ++j)
                acc[i][j] = __builtin_amdgcn_mfma_f32_16x16x32_bf16(af[i], bfr[j], acc[i][j], 0, 0, 0);
        __builtin_amdgcn_s_setprio(0);

        if (kt < NST - 2) {
            asm volatile("s_waitcnt vmcnt(4)" ::: "memory");
        } else {
            asm volatile("s_waitcnt vmcnt(0)" ::: "memory");
        }
        __builtin_amdgcn_s_barrier();
        __builtin_amdgcn_sched_barrier(0);

        ushort* o = cur; cur = nxt; nxt = tgt; tgt = o;
    }
#undef GEMM_STAGE
}

// ---------------------------------------------------------------- QKV GEMM
// Q pre-scaled by 0.125*log2(e): scores exit QK^T in log2 domain (exp2 softmax).
// 1D grid (1536 blocks) + bijective XCD swizzle.
__global__ __launch_bounds__(256) void qkv_gemm(
    const ushort* __restrict__ xb, const ushort* __restrict__ wb,
    const float* __restrict__ bqkv,
    ushort* __restrict__ qo, ushort* __restrict__ ko, ushort* __restrict__ vto)
{
    __shared__ __align__(16) ushort L[24576];   // 48 KB ring
    f32x4 acc[4][4];
    const int lin = blockIdx.x;                  // 1536 = 8 * 192
    const int swz = (lin & 7) * 192 + (lin >> 3);
    const int m0 = (swz & 63) * 128;
    const int n0 = (swz >> 6) * 128;
    gemm_bt_core<1024>(xb, wb, m0, n0, L, acc);

    const int lane = threadIdx.x & 63, wave = threadIdx.x >> 6;
    const int wm = wave >> 1, wn = wave & 1;
    const int col = lane & 15, rg = lane >> 4;
    const float QSC = 0.125f * 1.4426950408889634f;
#pragma unroll
    for (int j = 0; j < 4; ++j) {
        const int n = n0 + wn * 64 + j * 16 + col;
        const int h = n / 192, f = n % 192;
        const float bias = bqkv[n];
#pragma unroll
        for (int i2 = 0; i2 < 4; ++i2) {
            const int mbase = m0 + wm * 64 + i2 * 16 + rg * 4;
            if (f < 128) {
#pragma unroll
                for (int v = 0; v < 4; ++v) {
                    const int m = mbase + v;
                    const int b = m >> 11, s = m & 2047;
                    const float val = acc[i2][j][v] + bias;
                    if (f < 64) qo[((uint64_t)(b * 16 + h) * 2048 + s) * 64 + f]        = f2b(val * QSC);
                    else        ko[((uint64_t)(b * 16 + h) * 2048 + s) * 64 + (f - 64)] = f2b(val);
                }
            } else {
                const int b = mbase >> 11, s = mbase & 2047;
                ushort4 pk;
                pk.x = f2b(acc[i2][j][0] + bias);
                pk.y = f2b(acc[i2][j][1] + bias);
                pk.z = f2b(acc[i2][j][2] + bias);
                pk.w = f2b(acc[i2][j][3] + bias);
                *(ushort4*)&vto[((uint64_t)(b * 16 + h) * 64 + (f - 128)) * 2048 + s] = pk;
            }
        }
    }
}

// ---------------------------------------------------------------- flash attention v11
// = v9 staging (validated 104 us twice; v10's 40KB/4-block variant REGRESSED to
//   118 us with WRITE_SIZE +18MB -- L2 pressure + short V slack; reverted)
// + VALU-thinned softmax (bit-exact):
//   * select 3->2 ops: keep = sbfe(~w, pos, 1); s_bits &= keep (masked -> +0.0
//     exactly, exp2(0)=1 exactly as before)
//   * P pack 3->1 op: truncating v_perm (bias cancels numerator/denominator)
__global__ __launch_bounds__(256, 3) void attn_kernel(
    const ushort* __restrict__ qa, const ushort* __restrict__ ka,
    const ushort* __restrict__ vta, const uint32_t* __restrict__ mbits,
    ushort* __restrict__ ctxo)
{
    __shared__ __align__(16) ushort LDSH[24576];   // 48 KB: 3 x (K 8KB + V 8KB)
    ushort* const Ks0 = LDSH;
    ushort* const Vt0 = LDSH + 4096;
    ushort* const Ks1 = LDSH + 8192;
    ushort* const Vt1 = LDSH + 12288;
    ushort* const Ks2 = LDSH + 16384;
    ushort* const Vt2 = LDSH + 20480;
    ushort* const CTX = LDSH;                      // 16 KB epilogue stage aliases slot 0

    // XCD swizzle: XCD = bid%8 (round-robin dispatch); give each XCD 8 bh x 16 qb
    const int bid = blockIdx.x;
    const int bh = (bid & 7) * 8 + (bid >> 7);
    const int qb = (bid >> 3) & 15;
    const int b = bh >> 4;
    const int tid = threadIdx.x, lane = tid & 63, wave = tid >> 6;
    const int col = lane & 15, rg = lane >> 4;

    const uint64_t bhoff = (uint64_t)bh * (S_ * 64);
    const ushort* qp = qa + bhoff + (uint64_t)qb * 128 * 64;
    const ushort* kp = ka + bhoff;
    const ushort* vp = vta + bhoff;                       // [64][2048]
    // mask words for this thread's two q-rows (i=0 -> mk0, i=1 -> mk1)
    const uint32_t* mk0 = mbits + ((uint64_t)(b * 32) * 2048 + qb * 128 + wave * 32 + col) * 2;
    const uint32_t* mk1 = mk0 + 32;                       // +16 rows

    // staging geometry: 8 LDS rows / instruction; per-lane source gather
    const int lr = lane >> 3;                 // row within 8-row group (= r&7)
    const int usw = (lane & 7) ^ lr;          // XOR-swizzled 16B unit
    const int r0s = wave * 16 + lr;           // t=0 LDS row
    const int r1s = r0s + 8;                  // t=1 LDS row
    // sigma(r): bits (k2,jj,rg,v) -> (k2,rg,jj,v)
    const int sg0 = (r0s & 32) | ((r0s & 12) << 1) | ((r0s & 16) >> 2) | (r0s & 3);
    const int sg1 = (r1s & 32) | ((r1s & 12) << 1) | ((r1s & 16) >> 2) | (r1s & 3);
    const int kb0 = sg0 * 64 + usw * 8;       // K source offsets (element units)
    const int kb1 = sg1 * 64 + usw * 8;
    const int vb0 = r0s * 2048 + usw * 8;     // V source offsets (rows natural)
    const int vb1 = r1s * 2048 + usw * 8;
    const int ldst0 = wave * 1024;            // LDS dst (elements)
    const int ldst1 = ldst0 + 512;

    // Q fragments straight from global (16B loads; no LDS round-trip)
    bf16x8 aq[2][2];
#pragma unroll
    for (int i = 0; i < 2; ++i)
#pragma unroll
        for (int k2 = 0; k2 < 2; ++k2)
            aq[i][k2] = *(const bf16x8*)&qp[(wave * 32 + i * 16 + col) * 64 + k2 * 32 + rg * 8];

    // prologue: prefetch kt=0 -> slot0, kt=1 -> slot1; mask kt=0/1 -> regs.
    gl2lds16(&kp[kb0], &Ks0[ldst0]);
    gl2lds16(&kp[kb1], &Ks0[ldst1]);
    gl2lds16(&vp[vb0], &Vt0[ldst0]);
    gl2lds16(&vp[vb1], &Vt0[ldst1]);
    uint2 m_cur0 = *(const uint2*)mk0;
    uint2 m_cur1 = *(const uint2*)mk1;
    gl2lds16(&kp[4096 + kb0], &Ks1[ldst0]);
    gl2lds16(&kp[4096 + kb1], &Ks1[ldst1]);
    gl2lds16(&vp[vb0 + 64], &Vt1[ldst0]);
    gl2lds16(&vp[vb1 + 64], &Vt1[ldst1]);
    uint2 m_nxt0 = *(const uint2*)(mk0 + 4096);
    uint2 m_nxt1 = *(const uint2*)(mk1 + 4096);
    uint2 m_new0 = m_nxt0, m_new1 = m_nxt1;
    // one-time full drain (keeps the count math simple; loop never drains)
    asm volatile("s_waitcnt vmcnt(0)" ::: "memory");
    __builtin_amdgcn_s_barrier();
    __builtin_amdgcn_sched_barrier(0);

    const f32x4 fz = {0.f, 0.f, 0.f, 0.f};
    f32x4 acc[4][2];                      // ctx^T: row=d, col=q (q = wave*32 + i*16 + col)
#pragma unroll
    for (int dt = 0; dt < 4; ++dt)
#pragma unroll
        for (int i = 0; i < 2; ++i) acc[dt][i] = fz;
    f32x4 acc5[2] = {fz, fz};             // softmax denominator via ones-MFMA

    bf16x8 vone;
#pragma unroll
    for (int e = 0; e < 8; ++e) vone[e] = (short)0x3F80;   // bf16 1.0

    // precomputed bit positions: pos = rg*8 + p*4 + v
    int bpos[2][4];
#pragma unroll
    for (int p = 0; p < 2; ++p)
#pragma unroll
        for (int v = 0; v < 4; ++v) bpos[p][v] = rg * 8 + p * 4 + v;

    const int u0 = (rg ^ (col & 7)) << 3; // fragment read offset (k-units 0..31); other half ^32

    // ring pointers: c* = read at kt; n* = landing for kt+1; t* = issue target kt+2
    const ushort* cK = Ks0; const ushort* cV = Vt0;
    const ushort* nK = Ks1; const ushort* nV = Vt1;
    ushort* tK = Ks2; ushort* tV = Vt2;

    for (int kt = 0; kt < 32; ++kt) {
        // issue prefetch for kt+2 (distance 2): 4 gl2lds + 2 mask loads = 6 vmem ops
        if (kt < 30) {
            const int k2 = (kt + 2) * 4096;
            gl2lds16(&kp[k2 + kb0], &tK[ldst0]);
            gl2lds16(&kp[k2 + kb1], &tK[ldst1]);
            gl2lds16(&vp[vb0 + (kt + 2) * 64], &tV[ldst0]);
            gl2lds16(&vp[vb1 + (kt + 2) * 64], &tV[ldst1]);
            m_new0 = *(const uint2*)(mk0 + (uint64_t)(kt + 2) * 4096);
            m_new1 = *(const uint2*)(mk1 + (uint64_t)(kt + 2) * 4096);
        }

        // scores S^T (log2 domain) vs sigma-permuted keys
        f32x4 sc[2][4];
        __builtin_amdgcn_s_setprio(1);
#pragma unroll
        for (int j = 0; j < 4; ++j) {
            bf16x8 bk0 = *(const bf16x8*)&cK[(j * 16 + col) * 64 + u0];
            bf16x8 bk1 = *(const bf16x8*)&cK[(j * 16 + col) * 64 + (u0 ^ 32)];
#pragma unroll
            for (int i = 0; i < 2; ++i) {
                f32x4 z = __builtin_amdgcn_mfma_f32_16x16x32_bf16(bk0, aq[i][0], fz, 0, 0, 0);
                sc[i][j] = __builtin_amdgcn_mfma_f32_16x16x32_bf16(bk1, aq[i][1], z, 0, 0, 0);
            }
        }
        __builtin_amdgcn_s_setprio(0);

        // mask + exp2 (thinned): keep = sbfe(~w, pos, 1); s &= keep -> masked
        // lanes get +0.0 (exp2->1.0 exactly). Pack via truncating v_perm.
        // key held = (j&2)*16 + rg*8 + (j&1)*4 + v -> word j&2, bit rg*8+(j&1)*4+v.
        bf16x8 bp[2][2];
#pragma unroll
        for (int i = 0; i < 2; ++i) {
            const uint2 mw = i ? m_cur1 : m_cur0;
            const uint32_t wnx = ~mw.x, wny = ~mw.y;
            union { uint32_t w[4]; bf16x8 v; } p0, p1;
#pragma unroll
            for (int j = 0; j < 4; ++j) {
                const uint32_t wn = (j & 2) ? wny : wnx;
                const int p = j & 1;
                float pe[4];
#pragma unroll
                for (int v = 0; v < 4; ++v) {
                    union { float f; uint32_t u; } cu;
                    cu.f = sc[i][j][v];
                    cu.u &= keepmask(wn, bpos[p][v]);
                    pe[v] = EXP2(cu.f);
                }
                const uint32_t lo = pkbf_t(pe[0], pe[1]);
                const uint32_t hi = pkbf_t(pe[2], pe[3]);
                if (j < 2) { p0.w[p * 2] = lo; p0.w[p * 2 + 1] = hi; }
                else       { p1.w[p * 2] = lo; p1.w[p * 2 + 1] = hi; }
            }
            bp[i][0] = p0.v;
            bp[i][1] = p1.v;
        }

        // PV: acc[d][q] += Vt[d][k] * P[q][k]; denominator via ones-row MFMA
        __builtin_amdgcn_s_setprio(1);
#pragma unroll
        for (int i = 0; i < 2; ++i) {
            acc5[i] = __builtin_amdgcn_mfma_f32_16x16x32_bf16(vone, bp[i][0], acc5[i], 0, 0, 0);
            acc5[i] = __builtin_amdgcn_mfma_f32_16x16x32_bf16(vone, bp[i][1], acc5[i], 0, 0, 0);
        }
#pragma unroll
        for (int dt = 0; dt < 4; ++dt) {
            bf16x8 av0 = *(const bf16x8*)&cV[(dt * 16 + col) * 64 + u0];
            bf16x8 av1 = *(const bf16x8*)&cV[(dt * 16 + col) * 64 + (u0 ^ 32)];
#pragma unroll
            for (int i = 0; i < 2; ++i) {
                acc[dt][i] = __builtin_amdgcn_mfma_f32_16x16x32_bf16(av0, bp[i][0], acc[dt][i], 0, 0, 0);
                acc[dt][i] = __builtin_amdgcn_mfma_f32_16x16x32_bf16(av1, bp[i][1], acc[dt][i], 0, 0, 0);
            }
        }
        __builtin_amdgcn_s_setprio(0);

        // counted-vmcnt barrier: keep THIS phase's 6 prefetch ops in flight;
        // everything older (the kt+1 buffer, issued last phase) must be done.
        if (kt < 30) {
            asm volatile("s_waitcnt vmcnt(6)" ::: "memory");
        } else {
            asm volatile("s_waitcnt vmcnt(0)" ::: "memory");
        }
        __builtin_amdgcn_s_barrier();
        __builtin_amdgcn_sched_barrier(0);

        // rotate ring + mask regs
        const ushort* oK = cK; const ushort* oV = cV;
        cK = nK; cV = nV; nK = tK; nV = tV; tK = (ushort*)oK; tV = (ushort*)oV;
        m_cur0 = m_nxt0; m_cur1 = m_nxt1; m_nxt0 = m_new0; m_nxt1 = m_new1;
    }

    // 1/l per q=col lane: every row of acc5 equals the denominator (ones-matrix rows)
    float linv[2];
#pragma unroll
    for (int i = 0; i < 2; ++i) linv[i] = 1.0f / acc5[i][0];

    // transpose ctx^T back through CTX (swizzled) for coalesced global store.
#pragma unroll
    for (int dt = 0; dt < 4; ++dt)
#pragma unroll
        for (int i = 0; i < 2; ++i) {
            const int q = wave * 32 + i * 16 + col;
            const int d = dt * 16 + rg * 4;
            const int gg = (d >> 3) ^ (q & 7);
            ushort4 pk;
            pk.x = f2b(acc[dt][i][0] * linv[i]);
            pk.y = f2b(acc[dt][i][1] * linv[i]);
            pk.z = f2b(acc[dt][i][2] * linv[i]);
            pk.w = f2b(acc[dt][i][3] * linv[i]);
            *(ushort4*)&CTX[q * 64 + gg * 8 + (d & 7)] = pk;
        }
    __syncthreads();
    const int h = bh & 15;
    const uint64_t obase = (uint64_t)(b * S_ + qb * 128) * E_ + (uint64_t)h * 64;
#pragma unroll
    for (int t4 = 0; t4 < 4; ++t4) {
        const int id = tid + t4 * 256;
        const int r = id >> 3, c8 = id & 7;
        *(bf16x8*)&ctxo[obase + (uint64_t)r * E_ + c8 * 8] =
            *(const bf16x8*)&CTX[r * 64 + ((c8 ^ (r & 7)) << 3)];
    }
}

// ---------------------------------------------------------------- output GEMM
// 1D grid (512 blocks) + bijective XCD swizzle (512 = 8 * 64).
__global__ __launch_bounds__(256) void out_gemm(
    const ushort* __restrict__ ctxb, const ushort* __restrict__ wob,
    const float* __restrict__ bo, float* __restrict__ out)
{
    __shared__ __align__(16) ushort L[24576];   // 48 KB ring
    f32x4 acc[4][4];
    const int lin = blockIdx.x;
    const int swz = (lin & 7) * 64 + (lin >> 3);
    const int m0 = (swz & 63) * 128;
    const int n0 = (swz >> 6) * 128;
    gemm_bt_core<1024>(ctxb, wob, m0, n0, L, acc);

    const int lane = threadIdx.x & 63, wave = threadIdx.x >> 6;
    const int wm = wave >> 1, wn = wave & 1;
    const int col = lane & 15, rg = lane >> 4;
#pragma unroll
    for (int j = 0; j < 4; ++j) {
        const int n = n0 + wn * 64 + j * 16 + col;
        const float bias = bo[n];
#pragma unroll
        for (int i2 = 0; i2 < 4; ++i2) {
            const int mb2 = m0 + wm * 64 + i2 * 16 + rg * 4;
#pragma unroll
            for (int v = 0; v < 4; ++v)
                out[(uint64_t)(mb2 + v) * 1024 + n] = acc[i2][j][v] + bias;
        }
    }
}

// ---------------------------------------------------------------- launch
extern "C" void kernel_launch(void* const* d_in, const int* in_sizes, int n_in,
                              void* d_out, int out_size, void* d_ws, size_t ws_size,
                              hipStream_t stream)
{
    const float* x    = (const float*)d_in[0];
    const int*   mask = (const int*)d_in[1];
    const float* Wqkv = (const float*)d_in[2];
    const float* bqkv = (const float*)d_in[3];
    const float* Wo   = (const float*)d_in[4];
    const float* bo   = (const float*)d_in[5];
    float* out = (float*)d_out;

    char* p = (char*)d_ws;
    ushort* xb  = (ushort*)p; p += (size_t)8388608 * 2;   // x bf16 [8192][1024]
    ushort* wqb = (ushort*)p; p += (size_t)3145728 * 2;   // Wqkv bf16 [3072][1024]
    ushort* wob = (ushort*)p; p += (size_t)1048576 * 2;   // Wo bf16 [1024][1024]
    ushort* qo  = (ushort*)p; p += (size_t)8388608 * 2;   // Q bf16 (log2-domain prescale)
    ushort* ko  = (ushort*)p; p += (size_t)8388608 * 2;   // K bf16 [bh][s][64]
    ushort* vto = (ushort*)p; p += (size_t)8388608 * 2;   // V^T bf16 [bh][64][s]
    ushort* ctx = (ushort*)p; p += (size_t)8388608 * 2;   // ctx bf16 [8192][1024]
    uint32_t* mb = (uint32_t*)p;                          // packed mask bits (kt-major), 2 MB

    cvt_all<<<12288, 256, 0, stream>>>(x, Wqkv, Wo, xb, wqb, wob);
    pack_mask<<<65536, 256, 0, stream>>>(mask, mb);
    qkv_gemm<<<1536, 256, 0, stream>>>(xb, wqb, bqkv, qo, ko, vto);
    attn_kernel<<<1024, 256, 0, stream>>>(qo, ko, vto, mb, ctx);
    out_gemm<<<512, 256, 0, stream>>>(ctx, wob, bo, out);
}